// Round 16
// baseline (116.228 us; speedup 1.0000x reference)
//
#include <hip/hip_runtime.h>
#include <hip/hip_bf16.h>
#include <stdint.h>

#define BB 32
#define TT 4096
#define DD 64
#define SS 128
#define HH 512

#define SC_W 8
#define SC_L 32
// chains/(b,dir) = 128; 16 chains per WG; WGs = 32*2*8 = 512 (2 per CU)

typedef __attribute__((ext_vector_type(4))) float f32x4;
typedef __attribute__((ext_vector_type(8))) short s16x8;
typedef __attribute__((ext_vector_type(4))) short s16x4;

__device__ __forceinline__ ushort f2bfu(float x) {
    uint32_t b = __float_as_uint(x);
    uint32_t r = (b + 0x7FFFu + ((b >> 16) & 1u)) >> 16;
    return (ushort)r;
}
__device__ __forceinline__ float bfu2f(ushort u) {
    return __uint_as_float(((uint32_t)u) << 16);
}

// ---------------------------------------------------------------------------
// Prep: PfT[k][i] = softmax_row_i(trans)[k]; PbT[s][i] = softmax_col_i(trans)[s]
// ---------------------------------------------------------------------------
__global__ __launch_bounds__(128) void prep_trans(const float* __restrict__ tr,
                                                  float* __restrict__ PfT,
                                                  float* __restrict__ PbT) {
    int i = blockIdx.x & 127;
    int back = blockIdx.x >> 7;
    int j = threadIdx.x;
    float v = back ? tr[j * SS + i] : tr[i * SS + j];
    __shared__ float sh[4];
    float mx = v;
#pragma unroll
    for (int off = 32; off; off >>= 1) mx = fmaxf(mx, __shfl_xor(mx, off));
    if ((threadIdx.x & 63) == 0) sh[threadIdx.x >> 6] = mx;
    __syncthreads();
    mx = fmaxf(sh[0], sh[1]);
    float e = __expf(v - mx);
    float ssum = e;
#pragma unroll
    for (int off = 32; off; off >>= 1) ssum += __shfl_xor(ssum, off);
    if ((threadIdx.x & 63) == 0) sh[2 + (threadIdx.x >> 6)] = ssum;
    __syncthreads();
    float out = e / (sh[2] + sh[3]);
    if (back) PbT[j * SS + i] = out;
    else      PfT[j * SS + i] = out;
}

// ---------------------------------------------------------------------------
// conv_w: fragment-swizzled bf16 weight layouts (round 10; indices unchanged:
// f1 = htile*2 + kt, f2 = sg*32 + si*16 + kt).
// ---------------------------------------------------------------------------
__global__ __launch_bounds__(256) void conv_w(const float* __restrict__ w1,
                                              const float* __restrict__ w2,
                                              ushort* __restrict__ w1f,
                                              ushort* __restrict__ w2f) {
    int i = blockIdx.x * 256 + threadIdx.x;   // 48 WGs * 256 = 12288 threads
    if (i < 4096) {                           // w1: 64 frags x 64 lanes
        int f1 = i >> 6, l = i & 63;
        int kt = f1 & 1, htile = f1 >> 1;
        int row = htile * 16 + (l & 15);
        int col = kt * 32 + (l >> 4) * 8;
        const float* src = w1 + row * DD + col;
        ushort* dst = w1f + i * 8;
#pragma unroll
        for (int j = 0; j < 8; ++j) dst[j] = f2bfu(src[j]);
    } else if (i < 4096 + 8192) {             // w2: 128 frags x 64 lanes
        int i2 = i - 4096;
        int f2 = i2 >> 6, l = i2 & 63;
        int kt = f2 & 15, si = (f2 >> 4) & 1, sg = f2 >> 5;
        int row = sg * 32 + si * 16 + (l & 15);
        int col = kt * 32 + (l >> 4) * 8;
        const float* src = w2 + row * HH + col;
        ushort* dst = w2f + i2 * 8;
#pragma unroll
        for (int j = 0; j < 8; ++j) dst[j] = f2bfu(src[j]);
    }
}

// ---------------------------------------------------------------------------
// Fused MLP: E[b][t][s] (bf16) = exp( relu(obs@W1^T + b1) @ W2^T + b2 )
// 32 t-rows / 256 threads (4 waves) / 4 WG/CU (Hlds-only LDS = 33.5 KB).
// GEMM1 reads obs DIRECTLY from global (L1-resident 8KB tile) -> no Alds,
// no staging barrier; single barrier per WG (epi1 -> G2).
// ---------------------------------------------------------------------------
#define MLP_ROWS 32
__global__ __launch_bounds__(256, 4) void mlp_kernel(
    const float* __restrict__ obs, const ushort* __restrict__ w1f,
    const ushort* __restrict__ w2f, const float* __restrict__ b1,
    const float* __restrict__ b2, ushort* __restrict__ emitb) {
    __shared__ __align__(16) ushort Hlds[MLP_ROWS][524];   // 33.5 KB

    int wg = blockIdx.x;                  // 32 * 128 = 4096
    int bb = wg >> 7;
    int t0 = (wg & 127) * MLP_ROWS;
    int tid = threadIdx.x;
    int lane = tid & 63, wv = tid >> 6;   // wv 0..3
    int lhi = lane >> 4, llo = lane & 15;

    // ---- GEMM1T: H^T = W1 @ obs^T; wave wv owns h-tiles [wv*8, wv*8+8) ----
    const float* obsT = obs + ((size_t)bb * TT + t0) * DD;
    f32x4 acc1[8][2];
#pragma unroll
    for (int mi = 0; mi < 8; ++mi)
#pragma unroll
        for (int nt = 0; nt < 2; ++nt) acc1[mi][nt] = (f32x4){0.f, 0.f, 0.f, 0.f};
#pragma unroll
    for (int kt = 0; kt < 2; ++kt) {
        // obs B-fragments, fp32 global -> bf16 regs (L1-hot after first wave)
        s16x8 of[2];
#pragma unroll
        for (int nt = 0; nt < 2; ++nt) {
            const float* src = obsT + (nt * 16 + llo) * DD + kt * 32 + lhi * 8;
            float4 v0 = *(const float4*)(src);
            float4 v1 = *(const float4*)(src + 4);
            s16x8 pk;
            pk[0] = (short)f2bfu(v0.x); pk[1] = (short)f2bfu(v0.y);
            pk[2] = (short)f2bfu(v0.z); pk[3] = (short)f2bfu(v0.w);
            pk[4] = (short)f2bfu(v1.x); pk[5] = (short)f2bfu(v1.y);
            pk[6] = (short)f2bfu(v1.z); pk[7] = (short)f2bfu(v1.w);
            of[nt] = pk;
        }
#pragma unroll
        for (int mi = 0; mi < 8; ++mi) {
            int htile = wv * 8 + mi;
            s16x8 wf1 = *(const s16x8*)(w1f + (((htile * 2) + kt) * 64 + lane) * 8);
#pragma unroll
            for (int nt = 0; nt < 2; ++nt)
                acc1[mi][nt] = __builtin_amdgcn_mfma_f32_16x16x32_bf16(wf1, of[nt], acc1[mi][nt], 0, 0, 0);
        }
    }
    // epilogue 1: relu(+b1) -> Hlds[t][h], 4 consecutive h per lane = b64
#pragma unroll
    for (int mi = 0; mi < 8; ++mi) {
        int hb = (wv * 8 + mi) * 16 + lhi * 4;
        float4 b1v = *(const float4*)(b1 + hb);
#pragma unroll
        for (int nt = 0; nt < 2; ++nt) {
            s16x4 pk;
            pk[0] = (short)f2bfu(fmaxf(acc1[mi][nt][0] + b1v.x, 0.f));
            pk[1] = (short)f2bfu(fmaxf(acc1[mi][nt][1] + b1v.y, 0.f));
            pk[2] = (short)f2bfu(fmaxf(acc1[mi][nt][2] + b1v.z, 0.f));
            pk[3] = (short)f2bfu(fmaxf(acc1[mi][nt][3] + b1v.w, 0.f));
            *(s16x4*)(&Hlds[nt * 16 + llo][hb]) = pk;
        }
    }

    // ---- GEMM2 w2 prefetch: 4-deep ring, issued BEFORE the barrier ----
    int sg = wv;                          // wave = s-group of 32
    int sb = sg * 32;
    s16x8 wfr2[4][2];
#pragma unroll
    for (int kp = 0; kp < 4; ++kp)
#pragma unroll
        for (int si = 0; si < 2; ++si)
            wfr2[kp][si] = *(const s16x8*)(w2f + ((sg * 32 + si * 16 + kp) * 64 + lane) * 8);

    __syncthreads();

    // ---- GEMM2: eT[s][t] = W2 @ H^T; wave covers 32 s x 32 t ----
    f32x4 acc2[2][2];
#pragma unroll
    for (int si = 0; si < 2; ++si)
#pragma unroll
        for (int nt = 0; nt < 2; ++nt) acc2[si][nt] = (f32x4){0.f, 0.f, 0.f, 0.f};
#pragma unroll
    for (int kt = 0; kt < 16; ++kt) {
        s16x8 hf[2];
#pragma unroll
        for (int nt = 0; nt < 2; ++nt)
            hf[nt] = *(const s16x8*)(&Hlds[nt * 16 + llo][kt * 32 + lhi * 8]);
#pragma unroll
        for (int si = 0; si < 2; ++si)
#pragma unroll
            for (int nt = 0; nt < 2; ++nt)
                acc2[si][nt] = __builtin_amdgcn_mfma_f32_16x16x32_bf16(wfr2[kt & 3][si], hf[nt], acc2[si][nt], 0, 0, 0);
        if (kt < 12) {
#pragma unroll
            for (int si = 0; si < 2; ++si)
                wfr2[kt & 3][si] = *(const s16x8*)(w2f + ((sg * 32 + si * 16 + (kt + 4)) * 64 + lane) * 8);
        }
    }
    // epilogue 2: +b2, exp -> E[b][t][s] bf16
#pragma unroll
    for (int si = 0; si < 2; ++si) {
        int sbase = sb + si * 16 + lhi * 4;
        float4 b2v = *(const float4*)(b2 + sbase);
#pragma unroll
        for (int nt = 0; nt < 2; ++nt) {
            int tl = nt * 16 + llo;
            ushort* dst = emitb + ((size_t)bb * TT + t0 + tl) * SS + sbase;
            s16x4 pk;
            pk[0] = (short)f2bfu(__expf(acc2[si][nt][0] + b2v.x));
            pk[1] = (short)f2bfu(__expf(acc2[si][nt][1] + b2v.y));
            pk[2] = (short)f2bfu(__expf(acc2[si][nt][2] + b2v.z));
            pk[3] = (short)f2bfu(__expf(acc2[si][nt][3] + b2v.w));
            *(s16x4*)dst = pk;
        }
    }
}

// ---------------------------------------------------------------------------
// MFMA-batched linear-space scan. L=32, W=8: 512 WGs (2/CU) x 40 steps.
// A operand plain bf16; P hi+lo split (HH + HL streams); pointer-walk main
// loop; bf16 alpha/beta stores. (round-15 configuration, unchanged)
// ---------------------------------------------------------------------------
__global__ __launch_bounds__(256, 2) void scan_mfma(
    const ushort* __restrict__ Eb, const float* __restrict__ PfT,
    const float* __restrict__ PbT, ushort* __restrict__ galpha,
    ushort* __restrict__ gbeta) {
    int wg = blockIdx.x;            // 32 b * 2 dir * 8 = 512
    int b = wg >> 4;
    int dir = (wg >> 3) & 1;
    int wgc = wg & 7;
    int resetRow = (dir == 0) ? (wgc == 0 ? 0 : -1) : (wgc == 7 ? 15 : -1);
    int tid = threadIdx.x;
    int l = tid & 63, w = tid >> 6;
    int l15 = l & 15, g = l >> 4;
    int d = dir ? -1 : 1;

    const float* PT = dir ? PbT : PfT;
    ushort* paB = (dir ? gbeta : galpha) + (size_t)b * TT * SS;
    const ushort* EbB = Eb + (size_t)b * TT * SS;

    int col0 = w * 32 + l15;
    int col1 = col0 + 16;

    // static B fragments: PT[s][k] split into bf16 hi + lo
    s16x8 Bhi[2][4], Blo[2][4];
#pragma unroll
    for (int tile = 0; tile < 2; ++tile) {
        int srow = w * 32 + tile * 16 + l15;
#pragma unroll
        for (int kt = 0; kt < 4; ++kt) {
            const float* src = PT + srow * SS + kt * 32 + g * 8;
            float x[8];
            *(float4*)(x) = *(const float4*)(src);
            *(float4*)(x + 4) = *(const float4*)(src + 4);
            s16x8 hi, lo;
#pragma unroll
            for (int j = 0; j < 8; ++j) {
                uint32_t bx = __float_as_uint(x[j]);
                uint32_t hb = bx & 0xFFFF0000u;
                float rem = x[j] - __uint_as_float(hb);
                hi[j] = (short)(hb >> 16);
                lo[j] = (short)f2bfu(rem);
            }
            Bhi[tile][kt] = hi; Blo[tile][kt] = lo;
        }
    }
#pragma unroll
    for (int tile = 0; tile < 2; ++tile)
#pragma unroll
        for (int kt = 0; kt < 4; ++kt) {
            asm volatile("" : "+v"(Bhi[tile][kt]));
            asm volatile("" : "+v"(Blo[tile][kt]));
        }

    __shared__ __align__(16) ushort Ah[2][16][136];
    __shared__ __align__(16) float mscale[2][16];

    // init p = 1.0 (bf16)
    for (int i = tid; i < 16 * 136; i += 256) (&Ah[0][0][0])[i] = (ushort)0x3F80;
    if (tid < 16) mscale[0][tid] = 1.0f;

    int tj[4];
#pragma unroll
    for (int j = 0; j < 4; ++j) {
        int chain = wgc * 16 + 4 * g + j;
        tj[j] = dir ? chain * SC_L + (SC_L - 1) + SC_W : chain * SC_L - SC_W;
    }

    __syncthreads();

    ushort EA[8], EB[8];
#pragma unroll
    for (int j = 0; j < 4; ++j) {
        int tc = tj[j] < 0 ? 0 : (tj[j] > TT - 1 ? TT - 1 : tj[j]);
        uint32_t ro = (uint32_t)tc << 7;
        EA[j] = EbB[ro + col0];
        EA[4 + j] = EbB[ro + col1];
    }

#define SCAN_CORE(par, EC)                                                       \
        s16x8 ahi[4];                                                            \
        _Pragma("unroll") for (int kt = 0; kt < 4; ++kt)                         \
            ahi[kt] = *(const s16x8*)(&Ah[par][l15][kt * 32 + g * 8]);           \
        f32x4 rs = *(const f32x4*)(&mscale[par][4 * g]);                         \
        f32x4 acc0 = {0.f, 0.f, 0.f, 0.f}, acc1 = {0.f, 0.f, 0.f, 0.f};          \
        __builtin_amdgcn_s_setprio(1);                                           \
        _Pragma("unroll") for (int kt = 0; kt < 4; ++kt) {                       \
            acc0 = __builtin_amdgcn_mfma_f32_16x16x32_bf16(ahi[kt], Bhi[0][kt], acc0, 0, 0, 0); \
            acc1 = __builtin_amdgcn_mfma_f32_16x16x32_bf16(ahi[kt], Bhi[1][kt], acc1, 0, 0, 0); \
        }                                                                        \
        _Pragma("unroll") for (int kt = 0; kt < 4; ++kt) {                       \
            acc0 = __builtin_amdgcn_mfma_f32_16x16x32_bf16(ahi[kt], Blo[0][kt], acc0, 0, 0, 0); \
            acc1 = __builtin_amdgcn_mfma_f32_16x16x32_bf16(ahi[kt], Blo[1][kt], acc1, 0, 0, 0); \
        }                                                                        \
        __builtin_amdgcn_s_setprio(0);

#define SCAN_TAIL(par, pv)                                                       \
        _Pragma("unroll") for (int j = 0; j < 4; ++j) {   /* write A(v+1) */     \
            int rr = 4 * g + j;                                                  \
            Ah[(par) ^ 1][rr][col0] = f2bfu(pv[j]);                              \
            Ah[(par) ^ 1][rr][col1] = f2bfu(pv[4 + j]);                          \
        }                                                                        \
        if (w == 0 && l15 == 0) {                                                \
            f32x4 rn;                                                            \
            _Pragma("unroll") for (int j = 0; j < 4; ++j)                        \
                rn[j] = __builtin_amdgcn_rcpf(pv[j]);                            \
            *(f32x4*)(&mscale[(par) ^ 1][4 * g]) = rn;                           \
        }                                                                        \
        __builtin_amdgcn_sched_barrier(0);                                       \
        asm volatile("s_waitcnt lgkmcnt(0)" ::: "memory");                       \
        __builtin_amdgcn_s_barrier();                                            \
        __builtin_amdgcn_sched_barrier(0);

#define WARM_STEP(VSTEP, par, EC, EN)                                            \
    do {                                                                         \
        _Pragma("unroll") for (int j = 0; j < 4; ++j) {    /* E prefetch */      \
            int tn = tj[j] + d;                                                  \
            int tc = tn < 0 ? 0 : (tn > TT - 1 ? TT - 1 : tn);                   \
            uint32_t ro = (uint32_t)tc << 7;                                     \
            EN[j] = EbB[ro + col0];                                              \
            EN[4 + j] = EbB[ro + col1];                                          \
        }                                                                        \
        SCAN_CORE(par, EC)                                                       \
        float pv[8];                                                             \
        _Pragma("unroll") for (int j = 0; j < 4; ++j) {                          \
            pv[j] = acc0[j] * (bfu2f(EC[j]) * rs[j]);                            \
            pv[4 + j] = acc1[j] * (bfu2f(EC[4 + j]) * rs[j]);                    \
            if ((VSTEP) == SC_W - 1 && resetRow == 4 * g + j) {                  \
                pv[j] = 1.f; pv[4 + j] = 1.f;                                    \
            }                                                                    \
            tj[j] += d;                                                          \
        }                                                                        \
        SCAN_TAIL(par, pv)                                                       \
    } while (0)

#define MAIN_STEP(par, EC, EN)                                                   \
    do {                                                                         \
        _Pragma("unroll") for (int j = 0; j < 4; ++j) {    /* E prefetch */      \
            const char* eb = (const char*)EbB + (ptrdiff_t)vE[j];                \
            EN[j] = *(const ushort*)eb;                                          \
            EN[4 + j] = *(const ushort*)(eb + 32);                               \
            vE[j] += dstepE;                                                     \
        }                                                                        \
        SCAN_CORE(par, EC)                                                       \
        float pv[8];                                                             \
        _Pragma("unroll") for (int j = 0; j < 4; ++j) {                          \
            pv[j] = acc0[j] * (bfu2f(EC[j]) * rs[j]);                            \
            pv[4 + j] = acc1[j] * (bfu2f(EC[4 + j]) * rs[j]);                    \
            char* pb = (char*)paB + vP[j];                                       \
            *(ushort*)pb = f2bfu(pv[j]);                                         \
            *(ushort*)(pb + 32) = f2bfu(pv[4 + j]);                              \
            vP[j] += dstepE;                                                     \
        }                                                                        \
        SCAN_TAIL(par, pv)                                                       \
    } while (0)

    // warm: v = 0..SC_W-1 (clamped E addressing, no stores; reset at end)
    for (int v2 = 0; v2 < SC_W / 2; ++v2) {
        WARM_STEP(2 * v2, 0, EA, EB);
        WARM_STEP(2 * v2 + 1, 1, EB, EA);
    }

    // main: SC_L steps (pointer-walk, bf16 stores)
    int dstepE = d * 256;
    int vE[4];
    uint32_t vP[4];
#pragma unroll
    for (int j = 0; j < 4; ++j) {
        vE[j] = (tj[j] + d) * 256 + col0 * 2;
        vP[j] = (uint32_t)(tj[j] * 256 + col0 * 2);
    }
    for (int v2 = 0; v2 < SC_L / 2; ++v2) {
        MAIN_STEP(0, EA, EB);
        MAIN_STEP(1, EB, EA);
    }
#undef MAIN_STEP
#undef WARM_STEP
#undef SCAN_TAIL
#undef SCAN_CORE
}

// ---------------------------------------------------------------------------
// Combine (linear): out[b][t][s] = pa*pb / sum_s(pa*pb)   (bf16 inputs)
// ---------------------------------------------------------------------------
__global__ __launch_bounds__(256) void combine_kernel(
    const ushort* __restrict__ galpha, const ushort* __restrict__ gbeta,
    float* __restrict__ out) {
    int row = blockIdx.x * 4 + (threadIdx.x >> 6);
    int lane = threadIdx.x & 63;
    size_t base = (size_t)row * SS + lane * 2;
    ushort2 a = *(const ushort2*)(galpha + base);
    ushort2 b = *(const ushort2*)(gbeta + base);
    float g0 = bfu2f(a.x) * bfu2f(b.x);
    float g1 = bfu2f(a.y) * bfu2f(b.y);
    float ssum = g0 + g1;
#pragma unroll
    for (int off = 32; off; off >>= 1) ssum += __shfl_xor(ssum, off);
    float inv = 1.f / ssum;
    float2 o; o.x = g0 * inv; o.y = g1 * inv;
    *(float2*)(out + base) = o;
}

// ---------------------------------------------------------------------------
extern "C" void kernel_launch(void* const* d_in, const int* in_sizes, int n_in,
                              void* d_out, int out_size, void* d_ws, size_t ws_size,
                              hipStream_t stream) {
    const float* obs = (const float*)d_in[0];
    const float* trans = (const float*)d_in[1];
    const float* w1 = (const float*)d_in[2];
    const float* b1 = (const float*)d_in[3];
    const float* w2 = (const float*)d_in[4];
    const float* b2 = (const float*)d_in[5];

    char* ws = (char*)d_ws;
    float* PfT = (float*)(ws);                         // 64 KB
    float* PbT = (float*)(ws + 65536);                 // 64 KB
    ushort* w1f = (ushort*)(ws + 131072);              // 64 KB (fragment layout)
    ushort* w2f = (ushort*)(ws + 196608);              // 128 KB (fragment layout)
    ushort* emitb = (ushort*)(ws + 327680);            // 32 MB (E = exp(emit), bf16)
    ushort* galpha = (ushort*)(ws + 327680 + 33554432);              // 32 MB bf16
    ushort* gbeta = (ushort*)(ws + 327680 + 33554432 + 33554432);    // 32 MB bf16

    prep_trans<<<256, 128, 0, stream>>>(trans, PfT, PbT);
    conv_w<<<48, 256, 0, stream>>>(w1, w2, w1f, w2f);
    mlp_kernel<<<BB * (TT / MLP_ROWS), 256, 0, stream>>>(obs, w1f, w2f, b1, b2, emitb);
    scan_mfma<<<BB * 2 * 8, 256, 0, stream>>>(emitb, PfT, PbT, galpha, gbeta);
    combine_kernel<<<(BB * TT) / 4, 256, 0, stream>>>(galpha, gbeta, (float*)d_out);
}

// Round 17
// 103.669 us; speedup vs baseline: 1.1211x; 1.1211x over previous
//
#include <hip/hip_runtime.h>
#include <hip/hip_bf16.h>
#include <stdint.h>

#define BB 32
#define TT 4096
#define DD 64
#define SS 128
#define HH 512

#define SC_W 8
#define SC_L 32
// chains/(b,dir) = 128; 16 chains per WG; WGs = 32*2*8 = 512 (2 per CU)

typedef __attribute__((ext_vector_type(4))) float f32x4;
typedef __attribute__((ext_vector_type(8))) short s16x8;
typedef __attribute__((ext_vector_type(4))) short s16x4;

__device__ __forceinline__ ushort f2bfu(float x) {
    uint32_t b = __float_as_uint(x);
    uint32_t r = (b + 0x7FFFu + ((b >> 16) & 1u)) >> 16;
    return (ushort)r;
}
__device__ __forceinline__ float bfu2f(ushort u) {
    return __uint_as_float(((uint32_t)u) << 16);
}

// ---------------------------------------------------------------------------
// Prep: PfT[k][i] = softmax_row_i(trans)[k]; PbT[s][i] = softmax_col_i(trans)[s]
// ---------------------------------------------------------------------------
__global__ __launch_bounds__(128) void prep_trans(const float* __restrict__ tr,
                                                  float* __restrict__ PfT,
                                                  float* __restrict__ PbT) {
    int i = blockIdx.x & 127;
    int back = blockIdx.x >> 7;
    int j = threadIdx.x;
    float v = back ? tr[j * SS + i] : tr[i * SS + j];
    __shared__ float sh[4];
    float mx = v;
#pragma unroll
    for (int off = 32; off; off >>= 1) mx = fmaxf(mx, __shfl_xor(mx, off));
    if ((threadIdx.x & 63) == 0) sh[threadIdx.x >> 6] = mx;
    __syncthreads();
    mx = fmaxf(sh[0], sh[1]);
    float e = __expf(v - mx);
    float ssum = e;
#pragma unroll
    for (int off = 32; off; off >>= 1) ssum += __shfl_xor(ssum, off);
    if ((threadIdx.x & 63) == 0) sh[2 + (threadIdx.x >> 6)] = ssum;
    __syncthreads();
    float out = e / (sh[2] + sh[3]);
    if (back) PbT[j * SS + i] = out;
    else      PfT[j * SS + i] = out;
}

// ---------------------------------------------------------------------------
// conv_w: fragment-swizzled bf16 weight layouts (round 10).
// ---------------------------------------------------------------------------
__global__ __launch_bounds__(256) void conv_w(const float* __restrict__ w1,
                                              const float* __restrict__ w2,
                                              ushort* __restrict__ w1f,
                                              ushort* __restrict__ w2f) {
    int i = blockIdx.x * 256 + threadIdx.x;   // 48 WGs * 256 = 12288 threads
    if (i < 4096) {                           // w1: 64 frags x 64 lanes
        int f1 = i >> 6, l = i & 63;
        int kt = f1 & 1, htile = f1 >> 1;
        int row = htile * 16 + (l & 15);
        int col = kt * 32 + (l >> 4) * 8;
        const float* src = w1 + row * DD + col;
        ushort* dst = w1f + i * 8;
#pragma unroll
        for (int j = 0; j < 8; ++j) dst[j] = f2bfu(src[j]);
    } else if (i < 4096 + 8192) {             // w2: 128 frags x 64 lanes
        int i2 = i - 4096;
        int f2 = i2 >> 6, l = i2 & 63;
        int kt = f2 & 15, si = (f2 >> 4) & 1, sg = f2 >> 5;
        int row = sg * 32 + si * 16 + (l & 15);
        int col = kt * 32 + (l >> 4) * 8;
        const float* src = w2 + row * HH + col;
        ushort* dst = w2f + i2 * 8;
#pragma unroll
        for (int j = 0; j < 8; ++j) dst[j] = f2bfu(src[j]);
    }
}

// ---------------------------------------------------------------------------
// Fused MLP: E[b][t][s] (bf16) = exp( relu(obs@W1^T + b1) @ W2^T + b2 )
// Round-15 configuration (verified 44 us): 64 t-rows per WG, 512 threads
// (8 waves), 2 WG/CU. Alds staging + two barriers; fragment-swizzled weights;
// 4-deep w2 register ring. (r16's 32-row re-tile regressed: per-WG fixed
// costs doubled with WG count — amortization beats TLP here.)
// ---------------------------------------------------------------------------
#define MLP_ROWS 64
__global__ __launch_bounds__(512, 4) void mlp_kernel(
    const float* __restrict__ obs, const ushort* __restrict__ w1f,
    const ushort* __restrict__ w2f, const float* __restrict__ b1,
    const float* __restrict__ b2, ushort* __restrict__ emitb) {
    __shared__ __align__(16) ushort Alds[MLP_ROWS][72];
    __shared__ __align__(16) ushort Hlds[MLP_ROWS][524];

    int wg = blockIdx.x;                  // 32 * 64 = 2048
    int bb = wg >> 6;
    int t0 = (wg & 63) * MLP_ROWS;
    int tid = threadIdx.x;
    int lane = tid & 63, wv = tid >> 6;
    int lhi = lane >> 4, llo = lane & 15;

    {
        int r = tid >> 3, c0 = (tid & 7) * 8;
        const float* src = obs + ((size_t)bb * TT + t0 + r) * DD + c0;
        float4 v0 = *(const float4*)(src);
        float4 v1 = *(const float4*)(src + 4);
        s16x8 pk;
        pk[0] = (short)f2bfu(v0.x); pk[1] = (short)f2bfu(v0.y);
        pk[2] = (short)f2bfu(v0.z); pk[3] = (short)f2bfu(v0.w);
        pk[4] = (short)f2bfu(v1.x); pk[5] = (short)f2bfu(v1.y);
        pk[6] = (short)f2bfu(v1.z); pk[7] = (short)f2bfu(v1.w);
        *(s16x8*)(&Alds[r][c0]) = pk;
    }
    __syncthreads();

    int h0 = wv * 64;
    f32x4 acc1[4][4];
#pragma unroll
    for (int mi = 0; mi < 4; ++mi)
#pragma unroll
        for (int nt = 0; nt < 4; ++nt) acc1[mi][nt] = (f32x4){0.f, 0.f, 0.f, 0.f};
#pragma unroll
    for (int kt = 0; kt < 2; ++kt) {
        s16x8 wf1[4];
#pragma unroll
        for (int mi = 0; mi < 4; ++mi) {
            int htile = wv * 4 + mi;
            wf1[mi] = *(const s16x8*)(w1f + ((htile * 2 + kt) * 64 + lane) * 8);
        }
#pragma unroll
        for (int nt = 0; nt < 4; ++nt) {
            s16x8 of = *(const s16x8*)(&Alds[nt * 16 + llo][kt * 32 + lhi * 8]);
#pragma unroll
            for (int mi = 0; mi < 4; ++mi)
                acc1[mi][nt] = __builtin_amdgcn_mfma_f32_16x16x32_bf16(wf1[mi], of, acc1[mi][nt], 0, 0, 0);
        }
    }
#pragma unroll
    for (int mi = 0; mi < 4; ++mi) {
        float4 b1v = *(const float4*)(b1 + h0 + mi * 16 + lhi * 4);
#pragma unroll
        for (int nt = 0; nt < 4; ++nt) {
            s16x4 pk;
            pk[0] = (short)f2bfu(fmaxf(acc1[mi][nt][0] + b1v.x, 0.f));
            pk[1] = (short)f2bfu(fmaxf(acc1[mi][nt][1] + b1v.y, 0.f));
            pk[2] = (short)f2bfu(fmaxf(acc1[mi][nt][2] + b1v.z, 0.f));
            pk[3] = (short)f2bfu(fmaxf(acc1[mi][nt][3] + b1v.w, 0.f));
            *(s16x4*)(&Hlds[nt * 16 + llo][h0 + mi * 16 + lhi * 4]) = pk;
        }
    }

    int sg = wv >> 1, th = wv & 1;
    int sb = sg * 32;
    s16x8 wfr2[4][2];
#pragma unroll
    for (int kp = 0; kp < 4; ++kp)
#pragma unroll
        for (int si = 0; si < 2; ++si)
            wfr2[kp][si] = *(const s16x8*)(w2f + ((sg * 32 + si * 16 + kp) * 64 + lane) * 8);

    __syncthreads();

    f32x4 acc2[2][2];
#pragma unroll
    for (int si = 0; si < 2; ++si)
#pragma unroll
        for (int nt = 0; nt < 2; ++nt) acc2[si][nt] = (f32x4){0.f, 0.f, 0.f, 0.f};
#pragma unroll
    for (int kt = 0; kt < 16; ++kt) {
        s16x8 hf[2];
#pragma unroll
        for (int nt = 0; nt < 2; ++nt)
            hf[nt] = *(const s16x8*)(&Hlds[th * 32 + nt * 16 + llo][kt * 32 + lhi * 8]);
#pragma unroll
        for (int si = 0; si < 2; ++si)
#pragma unroll
            for (int nt = 0; nt < 2; ++nt)
                acc2[si][nt] = __builtin_amdgcn_mfma_f32_16x16x32_bf16(wfr2[kt & 3][si], hf[nt], acc2[si][nt], 0, 0, 0);
        if (kt < 12) {
#pragma unroll
            for (int si = 0; si < 2; ++si)
                wfr2[kt & 3][si] = *(const s16x8*)(w2f + ((sg * 32 + si * 16 + (kt + 4)) * 64 + lane) * 8);
        }
    }
#pragma unroll
    for (int si = 0; si < 2; ++si) {
        int sbase = sb + si * 16 + lhi * 4;
        float4 b2v = *(const float4*)(b2 + sbase);
#pragma unroll
        for (int nt = 0; nt < 2; ++nt) {
            int tl = th * 32 + nt * 16 + llo;
            ushort* dst = emitb + ((size_t)bb * TT + t0 + tl) * SS + sbase;
            s16x4 pk;
            pk[0] = (short)f2bfu(__expf(acc2[si][nt][0] + b2v.x));
            pk[1] = (short)f2bfu(__expf(acc2[si][nt][1] + b2v.y));
            pk[2] = (short)f2bfu(__expf(acc2[si][nt][2] + b2v.z));
            pk[3] = (short)f2bfu(__expf(acc2[si][nt][3] + b2v.w));
            *(s16x4*)dst = pk;
        }
    }
}

// ---------------------------------------------------------------------------
// MFMA-batched linear-space scan. L=32, W=8: 512 WGs (2/CU) x 40 steps.
// A operand plain bf16; P hi+lo split (HH + HL streams); pointer-walk main
// loop; bf16 alpha/beta stores. (round-15 configuration, unchanged)
// ---------------------------------------------------------------------------
__global__ __launch_bounds__(256, 2) void scan_mfma(
    const ushort* __restrict__ Eb, const float* __restrict__ PfT,
    const float* __restrict__ PbT, ushort* __restrict__ galpha,
    ushort* __restrict__ gbeta) {
    int wg = blockIdx.x;            // 32 b * 2 dir * 8 = 512
    int b = wg >> 4;
    int dir = (wg >> 3) & 1;
    int wgc = wg & 7;
    int resetRow = (dir == 0) ? (wgc == 0 ? 0 : -1) : (wgc == 7 ? 15 : -1);
    int tid = threadIdx.x;
    int l = tid & 63, w = tid >> 6;
    int l15 = l & 15, g = l >> 4;
    int d = dir ? -1 : 1;

    const float* PT = dir ? PbT : PfT;
    ushort* paB = (dir ? gbeta : galpha) + (size_t)b * TT * SS;
    const ushort* EbB = Eb + (size_t)b * TT * SS;

    int col0 = w * 32 + l15;
    int col1 = col0 + 16;

    // static B fragments: PT[s][k] split into bf16 hi + lo
    s16x8 Bhi[2][4], Blo[2][4];
#pragma unroll
    for (int tile = 0; tile < 2; ++tile) {
        int srow = w * 32 + tile * 16 + l15;
#pragma unroll
        for (int kt = 0; kt < 4; ++kt) {
            const float* src = PT + srow * SS + kt * 32 + g * 8;
            float x[8];
            *(float4*)(x) = *(const float4*)(src);
            *(float4*)(x + 4) = *(const float4*)(src + 4);
            s16x8 hi, lo;
#pragma unroll
            for (int j = 0; j < 8; ++j) {
                uint32_t bx = __float_as_uint(x[j]);
                uint32_t hb = bx & 0xFFFF0000u;
                float rem = x[j] - __uint_as_float(hb);
                hi[j] = (short)(hb >> 16);
                lo[j] = (short)f2bfu(rem);
            }
            Bhi[tile][kt] = hi; Blo[tile][kt] = lo;
        }
    }
#pragma unroll
    for (int tile = 0; tile < 2; ++tile)
#pragma unroll
        for (int kt = 0; kt < 4; ++kt) {
            asm volatile("" : "+v"(Bhi[tile][kt]));
            asm volatile("" : "+v"(Blo[tile][kt]));
        }

    __shared__ __align__(16) ushort Ah[2][16][136];
    __shared__ __align__(16) float mscale[2][16];

    // init p = 1.0 (bf16)
    for (int i = tid; i < 16 * 136; i += 256) (&Ah[0][0][0])[i] = (ushort)0x3F80;
    if (tid < 16) mscale[0][tid] = 1.0f;

    int tj[4];
#pragma unroll
    for (int j = 0; j < 4; ++j) {
        int chain = wgc * 16 + 4 * g + j;
        tj[j] = dir ? chain * SC_L + (SC_L - 1) + SC_W : chain * SC_L - SC_W;
    }

    __syncthreads();

    ushort EA[8], EB[8];
#pragma unroll
    for (int j = 0; j < 4; ++j) {
        int tc = tj[j] < 0 ? 0 : (tj[j] > TT - 1 ? TT - 1 : tj[j]);
        uint32_t ro = (uint32_t)tc << 7;
        EA[j] = EbB[ro + col0];
        EA[4 + j] = EbB[ro + col1];
    }

#define SCAN_CORE(par, EC)                                                       \
        s16x8 ahi[4];                                                            \
        _Pragma("unroll") for (int kt = 0; kt < 4; ++kt)                         \
            ahi[kt] = *(const s16x8*)(&Ah[par][l15][kt * 32 + g * 8]);           \
        f32x4 rs = *(const f32x4*)(&mscale[par][4 * g]);                         \
        f32x4 acc0 = {0.f, 0.f, 0.f, 0.f}, acc1 = {0.f, 0.f, 0.f, 0.f};          \
        __builtin_amdgcn_s_setprio(1);                                           \
        _Pragma("unroll") for (int kt = 0; kt < 4; ++kt) {                       \
            acc0 = __builtin_amdgcn_mfma_f32_16x16x32_bf16(ahi[kt], Bhi[0][kt], acc0, 0, 0, 0); \
            acc1 = __builtin_amdgcn_mfma_f32_16x16x32_bf16(ahi[kt], Bhi[1][kt], acc1, 0, 0, 0); \
        }                                                                        \
        _Pragma("unroll") for (int kt = 0; kt < 4; ++kt) {                       \
            acc0 = __builtin_amdgcn_mfma_f32_16x16x32_bf16(ahi[kt], Blo[0][kt], acc0, 0, 0, 0); \
            acc1 = __builtin_amdgcn_mfma_f32_16x16x32_bf16(ahi[kt], Blo[1][kt], acc1, 0, 0, 0); \
        }                                                                        \
        __builtin_amdgcn_s_setprio(0);

#define SCAN_TAIL(par, pv)                                                       \
        _Pragma("unroll") for (int j = 0; j < 4; ++j) {   /* write A(v+1) */     \
            int rr = 4 * g + j;                                                  \
            Ah[(par) ^ 1][rr][col0] = f2bfu(pv[j]);                              \
            Ah[(par) ^ 1][rr][col1] = f2bfu(pv[4 + j]);                          \
        }                                                                        \
        if (w == 0 && l15 == 0) {                                                \
            f32x4 rn;                                                            \
            _Pragma("unroll") for (int j = 0; j < 4; ++j)                        \
                rn[j] = __builtin_amdgcn_rcpf(pv[j]);                            \
            *(f32x4*)(&mscale[(par) ^ 1][4 * g]) = rn;                           \
        }                                                                        \
        __builtin_amdgcn_sched_barrier(0);                                       \
        asm volatile("s_waitcnt lgkmcnt(0)" ::: "memory");                       \
        __builtin_amdgcn_s_barrier();                                            \
        __builtin_amdgcn_sched_barrier(0);

#define WARM_STEP(VSTEP, par, EC, EN)                                            \
    do {                                                                         \
        _Pragma("unroll") for (int j = 0; j < 4; ++j) {    /* E prefetch */      \
            int tn = tj[j] + d;                                                  \
            int tc = tn < 0 ? 0 : (tn > TT - 1 ? TT - 1 : tn);                   \
            uint32_t ro = (uint32_t)tc << 7;                                     \
            EN[j] = EbB[ro + col0];                                              \
            EN[4 + j] = EbB[ro + col1];                                          \
        }                                                                        \
        SCAN_CORE(par, EC)                                                       \
        float pv[8];                                                             \
        _Pragma("unroll") for (int j = 0; j < 4; ++j) {                          \
            pv[j] = acc0[j] * (bfu2f(EC[j]) * rs[j]);                            \
            pv[4 + j] = acc1[j] * (bfu2f(EC[4 + j]) * rs[j]);                    \
            if ((VSTEP) == SC_W - 1 && resetRow == 4 * g + j) {                  \
                pv[j] = 1.f; pv[4 + j] = 1.f;                                    \
            }                                                                    \
            tj[j] += d;                                                          \
        }                                                                        \
        SCAN_TAIL(par, pv)                                                       \
    } while (0)

#define MAIN_STEP(par, EC, EN)                                                   \
    do {                                                                         \
        _Pragma("unroll") for (int j = 0; j < 4; ++j) {    /* E prefetch */      \
            const char* eb = (const char*)EbB + (ptrdiff_t)vE[j];                \
            EN[j] = *(const ushort*)eb;                                          \
            EN[4 + j] = *(const ushort*)(eb + 32);                               \
            vE[j] += dstepE;                                                     \
        }                                                                        \
        SCAN_CORE(par, EC)                                                       \
        float pv[8];                                                             \
        _Pragma("unroll") for (int j = 0; j < 4; ++j) {                          \
            pv[j] = acc0[j] * (bfu2f(EC[j]) * rs[j]);                            \
            pv[4 + j] = acc1[j] * (bfu2f(EC[4 + j]) * rs[j]);                    \
            char* pb = (char*)paB + vP[j];                                       \
            *(ushort*)pb = f2bfu(pv[j]);                                         \
            *(ushort*)(pb + 32) = f2bfu(pv[4 + j]);                              \
            vP[j] += dstepE;                                                     \
        }                                                                        \
        SCAN_TAIL(par, pv)                                                       \
    } while (0)

    // warm: v = 0..SC_W-1 (clamped E addressing, no stores; reset at end)
    for (int v2 = 0; v2 < SC_W / 2; ++v2) {
        WARM_STEP(2 * v2, 0, EA, EB);
        WARM_STEP(2 * v2 + 1, 1, EB, EA);
    }

    // main: SC_L steps (pointer-walk, bf16 stores)
    int dstepE = d * 256;
    int vE[4];
    uint32_t vP[4];
#pragma unroll
    for (int j = 0; j < 4; ++j) {
        vE[j] = (tj[j] + d) * 256 + col0 * 2;
        vP[j] = (uint32_t)(tj[j] * 256 + col0 * 2);
    }
    for (int v2 = 0; v2 < SC_L / 2; ++v2) {
        MAIN_STEP(0, EA, EB);
        MAIN_STEP(1, EB, EA);
    }
#undef MAIN_STEP
#undef WARM_STEP
#undef SCAN_TAIL
#undef SCAN_CORE
}

// ---------------------------------------------------------------------------
// Combine (linear): out[b][t][s] = pa*pb / sum_s(pa*pb)   (bf16 inputs)
// ---------------------------------------------------------------------------
__global__ __launch_bounds__(256) void combine_kernel(
    const ushort* __restrict__ galpha, const ushort* __restrict__ gbeta,
    float* __restrict__ out) {
    int row = blockIdx.x * 4 + (threadIdx.x >> 6);
    int lane = threadIdx.x & 63;
    size_t base = (size_t)row * SS + lane * 2;
    ushort2 a = *(const ushort2*)(galpha + base);
    ushort2 b = *(const ushort2*)(gbeta + base);
    float g0 = bfu2f(a.x) * bfu2f(b.x);
    float g1 = bfu2f(a.y) * bfu2f(b.y);
    float ssum = g0 + g1;
#pragma unroll
    for (int off = 32; off; off >>= 1) ssum += __shfl_xor(ssum, off);
    float inv = 1.f / ssum;
    float2 o; o.x = g0 * inv; o.y = g1 * inv;
    *(float2*)(out + base) = o;
}

// ---------------------------------------------------------------------------
extern "C" void kernel_launch(void* const* d_in, const int* in_sizes, int n_in,
                              void* d_out, int out_size, void* d_ws, size_t ws_size,
                              hipStream_t stream) {
    const float* obs = (const float*)d_in[0];
    const float* trans = (const float*)d_in[1];
    const float* w1 = (const float*)d_in[2];
    const float* b1 = (const float*)d_in[3];
    const float* w2 = (const float*)d_in[4];
    const float* b2 = (const float*)d_in[5];

    char* ws = (char*)d_ws;
    float* PfT = (float*)(ws);                         // 64 KB
    float* PbT = (float*)(ws + 65536);                 // 64 KB
    ushort* w1f = (ushort*)(ws + 131072);              // 64 KB (fragment layout)
    ushort* w2f = (ushort*)(ws + 196608);              // 128 KB (fragment layout)
    ushort* emitb = (ushort*)(ws + 327680);            // 32 MB (E = exp(emit), bf16)
    ushort* galpha = (ushort*)(ws + 327680 + 33554432);              // 32 MB bf16
    ushort* gbeta = (ushort*)(ws + 327680 + 33554432 + 33554432);    // 32 MB bf16

    prep_trans<<<256, 128, 0, stream>>>(trans, PfT, PbT);
    conv_w<<<48, 256, 0, stream>>>(w1, w2, w1f, w2f);
    mlp_kernel<<<BB * (TT / MLP_ROWS), 512, 0, stream>>>(obs, w1f, w2f, b1, b2, emitb);
    scan_mfma<<<BB * 2 * 8, 256, 0, stream>>>(emitb, PfT, PbT, galpha, gbeta);
    combine_kernel<<<(BB * TT) / 4, 256, 0, stream>>>(galpha, gbeta, (float*)d_out);
}